// Round 1
// baseline (659.745 us; speedup 1.0000x reference)
//
#include <hip/hip_runtime.h>

#define D_MODEL 2048
#define N_HEADS 16
#define DK 128
#define BATCH 4
#define SEQ 2048
#define BH (BATCH*N_HEADS)   // 64
#define M_TOT (BATCH*SEQ)    // 8192

typedef _Float16 half8 __attribute__((ext_vector_type(8)));
typedef _Float16 half4 __attribute__((ext_vector_type(4)));
typedef float f32x4 __attribute__((ext_vector_type(4)));

// ---------------- f32 -> f16 convert (vectorized) ----------------
__global__ void cvt_f32_f16(const float* __restrict__ src, _Float16* __restrict__ dst, int n8) {
  int i = blockIdx.x * blockDim.x + threadIdx.x;
  int stride = gridDim.x * blockDim.x;
  for (; i < n8; i += stride) {
    const float4* s = (const float4*)(src + (size_t)i * 8);
    float4 a = s[0], b = s[1];
    half8 h;
    h[0] = (_Float16)a.x; h[1] = (_Float16)a.y; h[2] = (_Float16)a.z; h[3] = (_Float16)a.w;
    h[4] = (_Float16)b.x; h[5] = (_Float16)b.y; h[6] = (_Float16)b.z; h[7] = (_Float16)b.w;
    *(half8*)(dst + (size_t)i * 8) = h;
  }
}

// ---------------- RoPE in-place on [bh][s][128] f16 ----------------
__global__ void rope_kernel(_Float16* __restrict__ t, const int* __restrict__ pos, int total) {
  int i = blockIdx.x * blockDim.x + threadIdx.x;
  int stride = gridDim.x * blockDim.x;
  const float l2t_over = 13.287712379549449f / 64.0f; // log2(10000)/64
  for (; i < total; i += stride) {
    int s = (i >> 6) & (SEQ - 1);
    int fi = i & 63;
    float inv = exp2f(-(float)fi * l2t_over);
    float ang = (float)pos[s] * inv;
    float c = cosf(ang), sn = sinf(ang);
    union { unsigned u; _Float16 h[2]; } uu;
    uu.u = ((unsigned*)t)[i];
    float t1 = (float)uu.h[0], t2 = (float)uu.h[1];
    uu.h[0] = (_Float16)(t1 * c - t2 * sn);
    uu.h[1] = (_Float16)(t1 * sn + t2 * c);
    ((unsigned*)t)[i] = uu.u;
  }
}

// ---------------- GEMM C = A @ Bt^T  (A[M][K], Bt[N][K], f16 MFMA) ----------------
#define BM 128
#define BN 128
#define BKT 64

__device__ __forceinline__ void gload_lds16(const void* g, void* l) {
  __builtin_amdgcn_global_load_lds(
      (const __attribute__((address_space(1))) unsigned int*)g,
      (__attribute__((address_space(3))) unsigned int*)l, 16, 0, 0);
}

// EPI: 0 = head layout f16 [bh][s][128]; 1 = Vt layout f16 [bh][128][s]; 2 = f32 row-major
template <int EPI>
__global__ __launch_bounds__(256) void gemm_bt(const _Float16* __restrict__ A,
                                               const _Float16* __restrict__ Bt,
                                               void* __restrict__ Cout,
                                               int M, int N, int K) {
  __shared__ _Float16 Al[BM * BKT];
  __shared__ _Float16 Bl[BN * BKT];
  const int tid = threadIdx.x;
  const int lane = tid & 63;
  const int w = tid >> 6;
  const int wr = w >> 1, wc = w & 1;
  const int nbx = N / BN;
  const int bx = blockIdx.x % nbx, by = blockIdx.x / nbx;
  const int m0 = by * BM, n0 = bx * BN;
  const int lr = lane & 15, lg = lane >> 4;

  f32x4 acc[4][4] = {};

  for (int k0 = 0; k0 < K; k0 += BKT) {
    __syncthreads();
#pragma unroll
    for (int c = 0; c < 4; ++c) {
      unsigned o = (unsigned)(c * 256 + tid) * 16;     // linear LDS byte offset
      unsigned row = o >> 7;                           // 128B per row (64 f16)
      unsigned colb = (o & 127u) ^ ((row & 7u) << 4);  // pre-swizzled source
      gload_lds16((const char*)A + ((size_t)(m0 + row) * K + k0) * 2 + colb, (char*)Al + o);
      gload_lds16((const char*)Bt + ((size_t)(n0 + row) * K + k0) * 2 + colb, (char*)Bl + o);
    }
    __syncthreads();
#pragma unroll
    for (int ks = 0; ks < 2; ++ks) {
      half8 a[4], b[4];
#pragma unroll
      for (int i = 0; i < 4; ++i) {
        unsigned rowA = wr * 64 + i * 16 + lr;
        unsigned off = rowA * 128 + (unsigned)(ks * 64 + lg * 16);
        off ^= (rowA & 7u) << 4;
        a[i] = *(const half8*)((const char*)Al + off);
        unsigned rowB = wc * 64 + i * 16 + lr;
        unsigned offb = rowB * 128 + (unsigned)(ks * 64 + lg * 16);
        offb ^= (rowB & 7u) << 4;
        b[i] = *(const half8*)((const char*)Bl + offb);
      }
#pragma unroll
      for (int i = 0; i < 4; ++i)
#pragma unroll
        for (int j = 0; j < 4; ++j)
          acc[i][j] = __builtin_amdgcn_mfma_f32_16x16x32_f16(a[i], b[j], acc[i][j], 0, 0, 0);
    }
  }

  // epilogue: D row=(lane>>4)*4+r (m-dim), col=lane&15 (n-dim)  [m89 verified]
#pragma unroll
  for (int i = 0; i < 4; ++i) {
    int row0 = m0 + wr * 64 + i * 16 + lg * 4;
#pragma unroll
    for (int j = 0; j < 4; ++j) {
      int col = n0 + wc * 64 + j * 16 + lr;
      if (EPI == 0) {
        _Float16* O = (_Float16*)Cout;
        int b = row0 >> 11, h = col >> 7, d = col & 127;
#pragma unroll
        for (int r = 0; r < 4; ++r) {
          int s = (row0 + r) & (SEQ - 1);
          O[((size_t)(b * N_HEADS + h) * SEQ + s) * DK + d] = (_Float16)acc[i][j][r];
        }
      } else if (EPI == 1) {
        _Float16* O = (_Float16*)Cout;
        int b = row0 >> 11, h = col >> 7, d = col & 127;
        int s = row0 & (SEQ - 1);
        half4 v;
        v[0] = (_Float16)acc[i][j][0]; v[1] = (_Float16)acc[i][j][1];
        v[2] = (_Float16)acc[i][j][2]; v[3] = (_Float16)acc[i][j][3];
        *(half4*)&O[((size_t)(b * N_HEADS + h) * DK + d) * SEQ + s] = v;
      } else {
        float* O = (float*)Cout;
#pragma unroll
        for (int r = 0; r < 4; ++r)
          O[(size_t)(row0 + r) * N + col] = acc[i][j][r];
      }
    }
  }
}

// ---------------- causal flash attention ----------------
// Q,K: [bh][s][128] f16 (roped); Vt: [bh][128][s] f16; ctx out: [b*S+s][h*128+d] f16
__global__ __launch_bounds__(256) void attn_kernel(const _Float16* __restrict__ Q,
                                                   const _Float16* __restrict__ Kb,
                                                   const _Float16* __restrict__ Vt,
                                                   _Float16* __restrict__ ctx) {
  __shared__ _Float16 Kl[64][136];   // keys x d, padded (272B stride)
  __shared__ _Float16 Vl[128][72];   // d x keys, padded (144B stride)
  __shared__ _Float16 Pl[4][16][72]; // per-wave P, padded

  const int tid = threadIdx.x, lane = tid & 63, w = tid >> 6;
  const int lr = lane & 15, lg = lane >> 4;
  const int bh = blockIdx.x & (BH - 1);
  const int qt = blockIdx.x >> 6;
  const int q0 = qt * 64;

  // Q fragments for this wave's 16 rows (held in regs all kernel)
  half8 qf[4];
  {
    const _Float16* qp = Q + ((size_t)bh * SEQ + q0 + w * 16 + lr) * DK + lg * 8;
#pragma unroll
    for (int ks = 0; ks < 4; ++ks) qf[ks] = *(const half8*)(qp + ks * 32);
  }

  f32x4 o_acc[8] = {};
  float mrow[4], lrow[4];
#pragma unroll
  for (int r = 0; r < 4; ++r) { mrow[r] = -3.0e38f; lrow[r] = 0.f; }
  const float scale = 0.08838834764831845f; // 1/sqrt(128)

  const int ntiles = qt + 1;
  for (int t = 0; t < ntiles; ++t) {
    __syncthreads();
    // stage K tile (64 x 256B rows) and Vt tile (128 x 128B rows)
    {
      const char* Kg = (const char*)(Kb + ((size_t)bh * SEQ + t * 64) * DK);
#pragma unroll
      for (int c = 0; c < 4; ++c) {
        int chunk = c * 256 + tid;
        int row = chunk >> 4, cb = (chunk & 15) * 16;
        uint4 v = *(const uint4*)(Kg + (size_t)row * 256 + cb);
        *(uint4*)((char*)&Kl[row][0] + cb) = v;
      }
      const char* Vg = (const char*)Vt + ((size_t)bh * DK * SEQ + t * 64) * 2;
#pragma unroll
      for (int c = 0; c < 4; ++c) {
        int chunk = c * 256 + tid;
        int d = chunk >> 3, cb = (chunk & 7) * 16;
        uint4 v = *(const uint4*)(Vg + (size_t)d * SEQ * 2 + cb);
        *(uint4*)((char*)&Vl[d][0] + cb) = v;
      }
    }
    __syncthreads();

    // QK^T: 16x64 scores per wave
    f32x4 sacc[4] = {};
#pragma unroll
    for (int nb = 0; nb < 4; ++nb)
#pragma unroll
      for (int ks = 0; ks < 4; ++ks) {
        half8 kf = *(const half8*)((const char*)&Kl[nb * 16 + lr][0] + ks * 64 + lg * 16);
        sacc[nb] = __builtin_amdgcn_mfma_f32_16x16x32_f16(qf[ks], kf, sacc[nb], 0, 0, 0);
      }

    // scale + causal mask + online softmax
    const bool diag = (t == qt);
    float pv[4][4], tmax[4];
#pragma unroll
    for (int r = 0; r < 4; ++r) tmax[r] = -3.0e38f;
#pragma unroll
    for (int nb = 0; nb < 4; ++nb) {
      int kglob = t * 64 + nb * 16 + lr;
#pragma unroll
      for (int r = 0; r < 4; ++r) {
        float vsc = sacc[nb][r] * scale;
        int qglob = q0 + w * 16 + lg * 4 + r;
        if (diag && kglob > qglob) vsc = -3.0e38f;
        pv[nb][r] = vsc;
        tmax[r] = fmaxf(tmax[r], vsc);
      }
    }
#pragma unroll
    for (int r = 0; r < 4; ++r) {
      float v = tmax[r];
      v = fmaxf(v, __shfl_xor(v, 1));
      v = fmaxf(v, __shfl_xor(v, 2));
      v = fmaxf(v, __shfl_xor(v, 4));
      v = fmaxf(v, __shfl_xor(v, 8));
      tmax[r] = v;
    }
    float sf[4];
#pragma unroll
    for (int r = 0; r < 4; ++r) {
      float mnew = fmaxf(mrow[r], tmax[r]);
      sf[r] = __expf(mrow[r] - mnew);
      mrow[r] = mnew;
      float ps = 0.f;
#pragma unroll
      for (int nb = 0; nb < 4; ++nb) {
        float p = __expf(pv[nb][r] - mnew);
        pv[nb][r] = p;
        ps += p;
      }
      ps += __shfl_xor(ps, 1);
      ps += __shfl_xor(ps, 2);
      ps += __shfl_xor(ps, 4);
      ps += __shfl_xor(ps, 8);
      lrow[r] = lrow[r] * sf[r] + ps;
    }
#pragma unroll
    for (int nb2 = 0; nb2 < 8; ++nb2)
#pragma unroll
      for (int r = 0; r < 4; ++r) o_acc[nb2][r] *= sf[r];

    // P -> per-wave LDS (C-layout -> A-layout redistribution)
#pragma unroll
    for (int nb = 0; nb < 4; ++nb)
#pragma unroll
      for (int r = 0; r < 4; ++r)
        Pl[w][lg * 4 + r][nb * 16 + lr] = (_Float16)pv[nb][r];
    asm volatile("s_waitcnt lgkmcnt(0)" ::: "memory");
    __builtin_amdgcn_sched_barrier(0);

    // PV: 16x128 += P(16x64) @ V(64x128)
#pragma unroll
    for (int kb = 0; kb < 2; ++kb) {
      half8 pa = *(const half8*)((const char*)&Pl[w][lr][0] + kb * 64 + lg * 16);
#pragma unroll
      for (int nb2 = 0; nb2 < 8; ++nb2) {
        half8 vf = *(const half8*)((const char*)&Vl[nb2 * 16 + lr][0] + kb * 64 + lg * 16);
        o_acc[nb2] = __builtin_amdgcn_mfma_f32_16x16x32_f16(pa, vf, o_acc[nb2], 0, 0, 0);
      }
    }
  }

  // epilogue: ctx[(b*S+s)*D + h*128 + d]
  const int b = bh >> 4, h = bh & 15;
#pragma unroll
  for (int r = 0; r < 4; ++r) {
    int s = q0 + w * 16 + lg * 4 + r;
    float invl = 1.0f / lrow[r];
    _Float16* op = ctx + ((size_t)(b * SEQ + s) * D_MODEL) + h * DK;
#pragma unroll
    for (int nb2 = 0; nb2 < 8; ++nb2)
      op[nb2 * 16 + lr] = (_Float16)(o_acc[nb2][r] * invl);
  }
}

// ---------------- launch ----------------
extern "C" void kernel_launch(void* const* d_in, const int* in_sizes, int n_in,
                              void* d_out, int out_size, void* d_ws, size_t ws_size,
                              hipStream_t stream) {
  const float* x = (const float*)d_in[0];
  const int* pos = (const int*)d_in[1];
  const float* Wq = (const float*)d_in[2];
  const float* Wk = (const float*)d_in[3];
  const float* Wv = (const float*)d_in[4];
  const float* Wo = (const float*)d_in[5];
  float* out = (float*)d_out;

  const size_t SZ_XH = (size_t)M_TOT * D_MODEL;   // 16.78M elems
  const size_t SZ_W = (size_t)D_MODEL * D_MODEL;  // 4.19M
  const size_t SZ_HEAD = (size_t)BH * SEQ * DK;   // 16.78M

  _Float16* xh = (_Float16*)d_ws;
  _Float16* wqh = xh + SZ_XH;
  _Float16* wkh = wqh + SZ_W;
  _Float16* wvh = wkh + SZ_W;
  _Float16* woh = wvh + SZ_W;
  _Float16* Qh = woh + SZ_W;
  _Float16* Kh = Qh + SZ_HEAD;
  _Float16* Vth = Kh + SZ_HEAD;
  _Float16* ctx = xh; // alias: xh dead after V GEMM

  cvt_f32_f16<<<2048, 256, 0, stream>>>(x, xh, (int)(SZ_XH / 8));
  cvt_f32_f16<<<2048, 256, 0, stream>>>(Wq, wqh, (int)(SZ_W / 8));
  cvt_f32_f16<<<2048, 256, 0, stream>>>(Wk, wkh, (int)(SZ_W / 8));
  cvt_f32_f16<<<2048, 256, 0, stream>>>(Wv, wvh, (int)(SZ_W / 8));
  cvt_f32_f16<<<2048, 256, 0, stream>>>(Wo, woh, (int)(SZ_W / 8));

  const int gblocks = (M_TOT / BM) * (D_MODEL / BN); // 64*16 = 1024
  gemm_bt<0><<<gblocks, 256, 0, stream>>>(xh, wqh, Qh, M_TOT, D_MODEL, D_MODEL);
  gemm_bt<0><<<gblocks, 256, 0, stream>>>(xh, wkh, Kh, M_TOT, D_MODEL, D_MODEL);
  gemm_bt<1><<<gblocks, 256, 0, stream>>>(xh, wvh, Vth, M_TOT, D_MODEL, D_MODEL);

  rope_kernel<<<4096, 256, 0, stream>>>(Qh, pos, BH * SEQ * 64);
  rope_kernel<<<4096, 256, 0, stream>>>(Kh, pos, BH * SEQ * 64);

  attn_kernel<<<(SEQ / 64) * BH, 256, 0, stream>>>(Qh, Kh, Vth, ctx);

  gemm_bt<2><<<gblocks, 256, 0, stream>>>(ctx, woh, out, M_TOT, D_MODEL, D_MODEL);
}

// Round 2
// 573.523 us; speedup vs baseline: 1.1503x; 1.1503x over previous
//
#include <hip/hip_runtime.h>

#define D_MODEL 2048
#define N_HEADS 16
#define DK 128
#define BATCH 4
#define SEQ 2048
#define BH (BATCH*N_HEADS)   // 64
#define M_TOT (BATCH*SEQ)    // 8192

typedef _Float16 half8 __attribute__((ext_vector_type(8)));
typedef _Float16 half4 __attribute__((ext_vector_type(4)));
typedef float f32x4 __attribute__((ext_vector_type(4)));

__device__ __forceinline__ void gload_lds16(const void* g, void* l) {
  __builtin_amdgcn_global_load_lds(
      (const __attribute__((address_space(1))) unsigned int*)g,
      (__attribute__((address_space(3))) unsigned int*)l, 16, 0, 0);
}

// ---------------- f32 -> f16 convert (vectorized) ----------------
__global__ void cvt_f32_f16(const float* __restrict__ src, _Float16* __restrict__ dst, int n8) {
  int i = blockIdx.x * blockDim.x + threadIdx.x;
  int stride = gridDim.x * blockDim.x;
  for (; i < n8; i += stride) {
    const float4* s = (const float4*)(src + (size_t)i * 8);
    float4 a = s[0], b = s[1];
    half8 h;
    h[0] = (_Float16)a.x; h[1] = (_Float16)a.y; h[2] = (_Float16)a.z; h[3] = (_Float16)a.w;
    h[4] = (_Float16)b.x; h[5] = (_Float16)b.y; h[6] = (_Float16)b.z; h[7] = (_Float16)b.w;
    *(half8*)(dst + (size_t)i * 8) = h;
  }
}

// 4 weight matrices (each SZ_W = 2^22 f32 = 2^19 chunks) -> contiguous f16 dst
__global__ void cvt4_f32_f16(const float* __restrict__ w0, const float* __restrict__ w1,
                             const float* __restrict__ w2, const float* __restrict__ w3,
                             _Float16* __restrict__ dst) {
  int i = blockIdx.x * blockDim.x + threadIdx.x;
  int stride = gridDim.x * blockDim.x;
  const int total = 4 << 19;
  for (; i < total; i += stride) {
    int which = i >> 19;
    int off = i & ((1 << 19) - 1);
    const float* s = which == 0 ? w0 : which == 1 ? w1 : which == 2 ? w2 : w3;
    const float4* sp = (const float4*)(s + (size_t)off * 8);
    float4 a = sp[0], b = sp[1];
    half8 h;
    h[0] = (_Float16)a.x; h[1] = (_Float16)a.y; h[2] = (_Float16)a.z; h[3] = (_Float16)a.w;
    h[4] = (_Float16)b.x; h[5] = (_Float16)b.y; h[6] = (_Float16)b.z; h[7] = (_Float16)b.w;
    *(half8*)(dst + (size_t)i * 8) = h;
  }
}

// ---------------- GEMM C = A @ Bt^T  (A[M][K], Bt[N][K], f16 MFMA) ----------------
#define BM 128
#define BN 128
#define BKT 64

// EPI: 0 = head layout f16 [bh][s][128] (optional fused RoPE);
//      1 = Vt layout f16 [bh][128][s]; 2 = f32 row-major
template <int EPI, bool ROPE>
__global__ __launch_bounds__(256) void gemm_bt(const _Float16* __restrict__ A,
                                               const _Float16* __restrict__ Bt,
                                               void* __restrict__ Cout,
                                               const int* __restrict__ pos,
                                               int M, int N, int K) {
  __shared__ _Float16 Al[BM * BKT];
  __shared__ _Float16 Bl[BN * BKT];
  const int tid = threadIdx.x;
  const int lane = tid & 63;
  const int w = tid >> 6;
  const int wr = w >> 1, wc = w & 1;
  const int nbx = N / BN;
  const int bx = blockIdx.x % nbx, by = blockIdx.x / nbx;
  const int m0 = by * BM, n0 = bx * BN;
  const int lr = lane & 15, lg = lane >> 4;

  f32x4 acc[4][4] = {};

  for (int k0 = 0; k0 < K; k0 += BKT) {
    __syncthreads();
#pragma unroll
    for (int c = 0; c < 4; ++c) {
      unsigned o = (unsigned)(c * 256 + tid) * 16;     // linear LDS byte offset
      unsigned row = o >> 7;                           // 128B per row (64 f16)
      unsigned colb = (o & 127u) ^ ((row & 7u) << 4);  // pre-swizzled source
      gload_lds16((const char*)A + ((size_t)(m0 + row) * K + k0) * 2 + colb, (char*)Al + o);
      gload_lds16((const char*)Bt + ((size_t)(n0 + row) * K + k0) * 2 + colb, (char*)Bl + o);
    }
    __syncthreads();
#pragma unroll
    for (int ks = 0; ks < 2; ++ks) {
      half8 a[4], b[4];
#pragma unroll
      for (int i = 0; i < 4; ++i) {
        unsigned rowA = wr * 64 + i * 16 + lr;
        unsigned off = rowA * 128 + (unsigned)(ks * 64 + lg * 16);
        off ^= (rowA & 7u) << 4;
        a[i] = *(const half8*)((const char*)Al + off);
        unsigned rowB = wc * 64 + i * 16 + lr;
        unsigned offb = rowB * 128 + (unsigned)(ks * 64 + lg * 16);
        offb ^= (rowB & 7u) << 4;
        b[i] = *(const half8*)((const char*)Bl + offb);
      }
#pragma unroll
      for (int i = 0; i < 4; ++i)
#pragma unroll
        for (int j = 0; j < 4; ++j)
          acc[i][j] = __builtin_amdgcn_mfma_f32_16x16x32_f16(a[i], b[j], acc[i][j], 0, 0, 0);
    }
  }

  // RoPE inv-freq per j (d depends on lr and j only)
  float inv[4];
  if (ROPE) {
#pragma unroll
    for (int j = 0; j < 4; ++j) {
      int d = (n0 + wc * 64 + j * 16 + lr) & 127;
      inv[j] = exp2f(-(float)(d >> 1) * (13.287712379549449f / 64.0f));
    }
  }

  // epilogue: D row=(lane>>4)*4+r (m-dim), col=lane&15 (n-dim)
#pragma unroll
  for (int i = 0; i < 4; ++i) {
    int row0 = m0 + wr * 64 + i * 16 + lg * 4;
#pragma unroll
    for (int j = 0; j < 4; ++j) {
      int col = n0 + wc * 64 + j * 16 + lr;
      if (EPI == 0) {
        _Float16* O = (_Float16*)Cout;
        int b = row0 >> 11, h = col >> 7, d = col & 127;
#pragma unroll
        for (int r = 0; r < 4; ++r) {
          int s = (row0 + r) & (SEQ - 1);
          float v = acc[i][j][r];
          if (ROPE) {
            float ang = (float)pos[s] * inv[j];
            float sn, cc;
            __sincosf(ang, &sn, &cc);
            float p = __shfl_xor(v, 1);
            v = (lr & 1) ? (v * cc + p * sn) : (v * cc - p * sn);
          }
          O[((size_t)(b * N_HEADS + h) * SEQ + s) * DK + d] = (_Float16)v;
        }
      } else if (EPI == 1) {
        _Float16* O = (_Float16*)Cout;
        int b = row0 >> 11, h = col >> 7, d = col & 127;
        int s = row0 & (SEQ - 1);
        half4 v;
        v[0] = (_Float16)acc[i][j][0]; v[1] = (_Float16)acc[i][j][1];
        v[2] = (_Float16)acc[i][j][2]; v[3] = (_Float16)acc[i][j][3];
        *(half4*)&O[((size_t)(b * N_HEADS + h) * DK + d) * SEQ + s] = v;
      } else {
        float* O = (float*)Cout;
#pragma unroll
        for (int r = 0; r < 4; ++r)
          O[(size_t)(row0 + r) * N + col] = acc[i][j][r];
      }
    }
  }
}

// ---------------- causal flash attention ----------------
// Q,K: [bh][s][128] f16 (roped); Vt: [bh][128][s] f16; ctx out: [b*S+s][h*128+d] f16
// 8 waves, QBLK=128 (16 q-rows/wave), KVBLK=64, double-buffered K/V via global_load_lds,
// XOR-swizzled LDS, heavy-first causal scheduling.
#define KVBLK 64
#define QBLK 128

__global__ __launch_bounds__(512, 4) void attn_kernel(const _Float16* __restrict__ Q,
                                                      const _Float16* __restrict__ Kg,
                                                      const _Float16* __restrict__ Vt,
                                                      _Float16* __restrict__ ctx) {
  __shared__ _Float16 Kl[2][KVBLK * DK];   // 2 x 16KB, rows 256B, XOR-swizzled
  __shared__ _Float16 Vl[2][DK * KVBLK];   // 2 x 16KB, rows 128B, XOR-swizzled
  __shared__ _Float16 Pl[8][16 * KVBLK];   // per-wave 2KB, rows 128B, XOR-swizzled

  const int tid = threadIdx.x, lane = tid & 63, w = tid >> 6;
  const int lr = lane & 15, lg = lane >> 4;
  const int bh = blockIdx.x & (BH - 1);
  const int qt = (SEQ / QBLK) - 1 - (blockIdx.x >> 6); // heavy-first
  const int q0 = qt * QBLK;
  const int nt = (q0 + QBLK) / KVBLK;

  const char* Kgb = (const char*)(Kg + (size_t)bh * SEQ * DK);
  const char* Vgb = (const char*)(Vt + (size_t)bh * DK * SEQ);

  // Q fragments: 16 rows per wave, held in regs
  half8 qf[4];
  {
    const _Float16* qp = Q + ((size_t)bh * SEQ + q0 + w * 16 + lr) * DK + lg * 8;
#pragma unroll
    for (int ks = 0; ks < 4; ++ks) qf[ks] = *(const half8*)(qp + ks * 32);
  }

  f32x4 o_acc[8] = {};
  float mrow[4], lrow[4];
#pragma unroll
  for (int r = 0; r < 4; ++r) { mrow[r] = -3.0e38f; lrow[r] = 0.f; }
  const float scale = 0.08838834764831845f; // 1/sqrt(128)

  auto stage = [&](int t, int buf) {
#pragma unroll
    for (int it = 0; it < 2; ++it) {
      int id = it * 512 + tid;
      {
        int row = id >> 4, cc = id & 15;
        int colb = (cc << 4) ^ ((row & 7) << 4);
        gload_lds16(Kgb + (size_t)(t * KVBLK + row) * 256 + colb,
                    (char*)&Kl[buf][0] + id * 16);
      }
      {
        int row = id >> 3, cc = id & 7;
        int colb = (cc << 4) ^ ((row & 7) << 4);
        gload_lds16(Vgb + (size_t)row * (SEQ * 2) + (size_t)t * (KVBLK * 2) + colb,
                    (char*)&Vl[buf][0] + id * 16);
      }
    }
  };

  stage(0, 0);
  asm volatile("s_waitcnt vmcnt(0)" ::: "memory");
  __syncthreads();

  int cur = 0;
  for (int t = 0; t < nt; ++t) {
    if (t + 1 < nt) stage(t + 1, cur ^ 1); // async prefetch, hidden under compute

    const char* Kc = (const char*)&Kl[cur][0];
    const char* Vc = (const char*)&Vl[cur][0];
    char* Pb = (char*)&Pl[w][0];

    // QK^T: 16x64 scores per wave
    f32x4 sacc[4] = {};
#pragma unroll
    for (int nb = 0; nb < 4; ++nb)
#pragma unroll
      for (int ks = 0; ks < 4; ++ks) {
        half8 kf = *(const half8*)(Kc + (nb * 16 + lr) * 256 +
                                   ((ks * 64 + lg * 16) ^ ((lr & 7) << 4)));
        sacc[nb] = __builtin_amdgcn_mfma_f32_16x16x32_f16(qf[ks], kf, sacc[nb], 0, 0, 0);
      }

    // scale + causal mask + per-row max (keys live on lr within 16-lane groups)
    const bool diag = (t >= nt - 2);
    float tmax[4];
#pragma unroll
    for (int r = 0; r < 4; ++r) tmax[r] = -3.0e38f;
#pragma unroll
    for (int nb = 0; nb < 4; ++nb) {
      int kglob = t * KVBLK + nb * 16 + lr;
#pragma unroll
      for (int r = 0; r < 4; ++r) {
        float vsc = sacc[nb][r] * scale;
        int qglob = q0 + w * 16 + lg * 4 + r;
        if (diag && kglob > qglob) vsc = -3.0e38f;
        sacc[nb][r] = vsc;
        tmax[r] = fmaxf(tmax[r], vsc);
      }
    }
#pragma unroll
    for (int r = 0; r < 4; ++r) {
      float v = tmax[r];
      v = fmaxf(v, __shfl_xor(v, 1));
      v = fmaxf(v, __shfl_xor(v, 2));
      v = fmaxf(v, __shfl_xor(v, 4));
      v = fmaxf(v, __shfl_xor(v, 8));
      tmax[r] = v;
    }
    float sf[4];
#pragma unroll
    for (int r = 0; r < 4; ++r) {
      float mnew = fmaxf(mrow[r], tmax[r]);
      sf[r] = __expf(mrow[r] - mnew);
      mrow[r] = mnew;
      float ps = 0.f;
#pragma unroll
      for (int nb = 0; nb < 4; ++nb) {
        float p = __expf(sacc[nb][r] - mnew);
        sacc[nb][r] = p;
        ps += p;
      }
      ps += __shfl_xor(ps, 1);
      ps += __shfl_xor(ps, 2);
      ps += __shfl_xor(ps, 4);
      ps += __shfl_xor(ps, 8);
      lrow[r] = lrow[r] * sf[r] + ps;
    }
#pragma unroll
    for (int nb2 = 0; nb2 < 8; ++nb2)
#pragma unroll
      for (int r = 0; r < 4; ++r) o_acc[nb2][r] *= sf[r];

    // P -> per-wave LDS (C-layout -> A-layout), XOR-swizzled rows of 128B
#pragma unroll
    for (int nb = 0; nb < 4; ++nb)
#pragma unroll
      for (int r = 0; r < 4; ++r) {
        int prow = lg * 4 + r;
        int pbyte = prow * 128 + (((nb * 16 + lr) * 2) ^ ((prow & 7) << 4));
        *(_Float16*)(Pb + pbyte) = (_Float16)sacc[nb][r];
      }
    asm volatile("s_waitcnt lgkmcnt(0)" ::: "memory");
    __builtin_amdgcn_sched_barrier(0);

    // PV: 16x128 += P(16x64) @ V(64x128)
#pragma unroll
    for (int kb = 0; kb < 2; ++kb) {
      half8 pa = *(const half8*)(Pb + lr * 128 +
                                 ((kb * 64 + lg * 16) ^ ((lr & 7) << 4)));
#pragma unroll
      for (int nb2 = 0; nb2 < 8; ++nb2) {
        half8 vf = *(const half8*)(Vc + (nb2 * 16 + lr) * 128 +
                                   ((kb * 64 + lg * 16) ^ ((lr & 7) << 4)));
        o_acc[nb2] = __builtin_amdgcn_mfma_f32_16x16x32_f16(pa, vf, o_acc[nb2], 0, 0, 0);
      }
    }

    asm volatile("s_waitcnt vmcnt(0)" ::: "memory");
    __syncthreads();
    cur ^= 1;
  }

  // epilogue: ctx[(b*S+s)*D + h*128 + d]
  const int b = bh >> 4, h = bh & 15;
#pragma unroll
  for (int r = 0; r < 4; ++r) {
    int s = q0 + w * 16 + lg * 4 + r;
    float invl = 1.0f / lrow[r];
    _Float16* op = ctx + ((size_t)(b * SEQ + s) * D_MODEL) + h * DK;
#pragma unroll
    for (int nb2 = 0; nb2 < 8; ++nb2)
      op[nb2 * 16 + lr] = (_Float16)(o_acc[nb2][r] * invl);
  }
}

// ---------------- launch ----------------
extern "C" void kernel_launch(void* const* d_in, const int* in_sizes, int n_in,
                              void* d_out, int out_size, void* d_ws, size_t ws_size,
                              hipStream_t stream) {
  const float* x = (const float*)d_in[0];
  const int* pos = (const int*)d_in[1];
  const float* Wq = (const float*)d_in[2];
  const float* Wk = (const float*)d_in[3];
  const float* Wv = (const float*)d_in[4];
  const float* Wo = (const float*)d_in[5];
  float* out = (float*)d_out;

  const size_t SZ_XH = (size_t)M_TOT * D_MODEL;   // 16.78M elems
  const size_t SZ_W = (size_t)D_MODEL * D_MODEL;  // 4.19M
  const size_t SZ_HEAD = (size_t)BH * SEQ * DK;   // 16.78M

  _Float16* xh = (_Float16*)d_ws;
  _Float16* wqh = xh + SZ_XH;
  _Float16* wkh = wqh + SZ_W;
  _Float16* wvh = wkh + SZ_W;
  _Float16* woh = wvh + SZ_W;
  _Float16* Qh = woh + SZ_W;
  _Float16* Kh = Qh + SZ_HEAD;
  _Float16* Vth = Kh + SZ_HEAD;
  _Float16* ctx = xh; // alias: xh dead after V GEMM

  cvt_f32_f16<<<2048, 256, 0, stream>>>(x, xh, (int)(SZ_XH / 8));
  cvt4_f32_f16<<<2048, 256, 0, stream>>>(Wq, Wk, Wv, Wo, wqh);

  const int gblocks = (M_TOT / BM) * (D_MODEL / BN); // 64*16 = 1024
  gemm_bt<0, true><<<gblocks, 256, 0, stream>>>(xh, wqh, Qh, pos, M_TOT, D_MODEL, D_MODEL);
  gemm_bt<0, true><<<gblocks, 256, 0, stream>>>(xh, wkh, Kh, pos, M_TOT, D_MODEL, D_MODEL);
  gemm_bt<1, false><<<gblocks, 256, 0, stream>>>(xh, wvh, Vth, nullptr, M_TOT, D_MODEL, D_MODEL);

  attn_kernel<<<(SEQ / QBLK) * BH, 512, 0, stream>>>(Qh, Kh, Vth, ctx);

  gemm_bt<2, false><<<gblocks, 256, 0, stream>>>(ctx, woh, out, nullptr, M_TOT, D_MODEL, D_MODEL);
}

// Round 3
// 500.068 us; speedup vs baseline: 1.3193x; 1.1469x over previous
//
#include <hip/hip_runtime.h>

#define D_MODEL 2048
#define N_HEADS 16
#define DK 128
#define BATCH 4
#define SEQ 2048
#define BH (BATCH*N_HEADS)   // 64
#define M_TOT (BATCH*SEQ)    // 8192
#define SZ_HEAD ((size_t)BH*SEQ*DK)

typedef _Float16 half8 __attribute__((ext_vector_type(8)));
typedef _Float16 half4 __attribute__((ext_vector_type(4)));
typedef _Float16 half2v __attribute__((ext_vector_type(2)));
typedef float f32x4 __attribute__((ext_vector_type(4)));
typedef float f32x16 __attribute__((ext_vector_type(16)));

__device__ __forceinline__ void gload_lds16(const void* g, void* l) {
  __builtin_amdgcn_global_load_lds(
      (const __attribute__((address_space(1))) unsigned int*)g,
      (__attribute__((address_space(3))) unsigned int*)l, 16, 0, 0);
}

// v_permlane32_swap_b32: a' = {a.lo | b.lo-from-partner}, b' = {a.hi-from-partner | b.hi}
__device__ __forceinline__ void plswap(unsigned& a, unsigned& b) {
  asm volatile("v_permlane32_swap_b32 %0, %1" : "+v"(a), "+v"(b));
}

// ---------------- f32 -> f16 convert (vectorized) ----------------
__global__ void cvt_f32_f16(const float* __restrict__ src, _Float16* __restrict__ dst, int n8) {
  int i = blockIdx.x * blockDim.x + threadIdx.x;
  int stride = gridDim.x * blockDim.x;
  for (; i < n8; i += stride) {
    const float4* s = (const float4*)(src + (size_t)i * 8);
    float4 a = s[0], b = s[1];
    half8 h;
    h[0] = (_Float16)a.x; h[1] = (_Float16)a.y; h[2] = (_Float16)a.z; h[3] = (_Float16)a.w;
    h[4] = (_Float16)b.x; h[5] = (_Float16)b.y; h[6] = (_Float16)b.z; h[7] = (_Float16)b.w;
    *(half8*)(dst + (size_t)i * 8) = h;
  }
}

__global__ void cvt4_f32_f16(const float* __restrict__ w0, const float* __restrict__ w1,
                             const float* __restrict__ w2, const float* __restrict__ w3,
                             _Float16* __restrict__ dst) {
  int i = blockIdx.x * blockDim.x + threadIdx.x;
  int stride = gridDim.x * blockDim.x;
  const int total = 4 << 19;
  for (; i < total; i += stride) {
    int which = i >> 19;
    int off = i & ((1 << 19) - 1);
    const float* s = which == 0 ? w0 : which == 1 ? w1 : which == 2 ? w2 : w3;
    const float4* sp = (const float4*)(s + (size_t)off * 8);
    float4 a = sp[0], b = sp[1];
    half8 h;
    h[0] = (_Float16)a.x; h[1] = (_Float16)a.y; h[2] = (_Float16)a.z; h[3] = (_Float16)a.w;
    h[4] = (_Float16)b.x; h[5] = (_Float16)b.y; h[6] = (_Float16)b.z; h[7] = (_Float16)b.w;
    *(half8*)(dst + (size_t)i * 8) = h;
  }
}

// ---------------- GEMM C = A @ Bt^T ----------------
#define BM 128
#define BN 128
#define BKT 64

// EPI: 2 = f32 row-major; 3 = fused QKV (Q/K roped heads, V transposed)
template <int EPI, bool ROPE>
__global__ __launch_bounds__(256) void gemm_bt(const _Float16* __restrict__ A,
                                               const _Float16* __restrict__ Bt,
                                               void* __restrict__ Cout,
                                               const int* __restrict__ pos,
                                               int M, int N, int K) {
  __shared__ _Float16 Al[BM * BKT];
  __shared__ _Float16 Bl[BN * BKT];
  const int tid = threadIdx.x;
  const int lane = tid & 63;
  const int w = tid >> 6;
  const int wr = w >> 1, wc = w & 1;
  const int nbx = N / BN;
  const int bx = blockIdx.x % nbx, by = blockIdx.x / nbx;
  const int m0 = by * BM, n0 = bx * BN;
  const int lr = lane & 15, lg = lane >> 4;

  f32x4 acc[4][4] = {};

  for (int k0 = 0; k0 < K; k0 += BKT) {
    __syncthreads();
#pragma unroll
    for (int c = 0; c < 4; ++c) {
      unsigned o = (unsigned)(c * 256 + tid) * 16;
      unsigned row = o >> 7;
      unsigned colb = (o & 127u) ^ ((row & 7u) << 4);
      gload_lds16((const char*)A + ((size_t)(m0 + row) * K + k0) * 2 + colb, (char*)Al + o);
      gload_lds16((const char*)Bt + ((size_t)(n0 + row) * K + k0) * 2 + colb, (char*)Bl + o);
    }
    __syncthreads();
#pragma unroll
    for (int ks = 0; ks < 2; ++ks) {
      half8 a[4], b[4];
#pragma unroll
      for (int i = 0; i < 4; ++i) {
        unsigned rowA = wr * 64 + i * 16 + lr;
        unsigned off = rowA * 128 + (unsigned)(ks * 64 + lg * 16);
        off ^= (rowA & 7u) << 4;
        a[i] = *(const half8*)((const char*)Al + off);
        unsigned rowB = wc * 64 + i * 16 + lr;
        unsigned offb = rowB * 128 + (unsigned)(ks * 64 + lg * 16);
        offb ^= (rowB & 7u) << 4;
        b[i] = *(const half8*)((const char*)Bl + offb);
      }
#pragma unroll
      for (int i = 0; i < 4; ++i)
#pragma unroll
        for (int j = 0; j < 4; ++j)
          acc[i][j] = __builtin_amdgcn_mfma_f32_16x16x32_f16(a[i], b[j], acc[i][j], 0, 0, 0);
    }
  }

  float inv[4];
  if (ROPE) {
#pragma unroll
    for (int j = 0; j < 4; ++j) {
      int d = (n0 + wc * 64 + j * 16 + lr) & 127;
      inv[j] = exp2f(-(float)(d >> 1) * (13.287712379549449f / 64.0f));
    }
  }

  const int which = (EPI == 3) ? (n0 >> 11) : 0; // 0=Q,1=K,2=V (block-uniform)

#pragma unroll
  for (int i = 0; i < 4; ++i) {
    int row0 = m0 + wr * 64 + i * 16 + lg * 4;
#pragma unroll
    for (int j = 0; j < 4; ++j) {
      int col = n0 + wc * 64 + j * 16 + lr;
      if (EPI == 3) {
        int h = (col >> 7) & 15, d = col & 127;
        int b = row0 >> 11;
        if (which < 2) {
          _Float16* O = (_Float16*)Cout + (size_t)which * SZ_HEAD;
#pragma unroll
          for (int r = 0; r < 4; ++r) {
            int s = (row0 + r) & (SEQ - 1);
            float v = acc[i][j][r];
            float ang = (float)pos[s] * inv[j];
            float sn, cc;
            __sincosf(ang, &sn, &cc);
            float p = __shfl_xor(v, 1);
            v = (lr & 1) ? (v * cc + p * sn) : (v * cc - p * sn);
            O[((size_t)(b * N_HEADS + h) * SEQ + s) * DK + d] = (_Float16)v;
          }
        } else {
          _Float16* O = (_Float16*)Cout + 2 * SZ_HEAD;
          int s = row0 & (SEQ - 1);
          half4 v;
          v[0] = (_Float16)acc[i][j][0]; v[1] = (_Float16)acc[i][j][1];
          v[2] = (_Float16)acc[i][j][2]; v[3] = (_Float16)acc[i][j][3];
          *(half4*)&O[((size_t)(b * N_HEADS + h) * DK + d) * SEQ + s] = v;
        }
      } else {
        float* O = (float*)Cout;
#pragma unroll
        for (int r = 0; r < 4; ++r)
          O[(size_t)(row0 + r) * N + col] = acc[i][j][r];
      }
    }
  }
}

// ---------------- causal flash attention (swapped-operand 32x32) ----------------
// Q,K: [bh][s][128] f16 roped; Vt: [bh][128][s] f16; ctx: [b*S+s][h*128+d] f16
// 8 waves x 32 q-rows = QBLK 256; KVBLK 64; S^T = mfma(K,Q) so each lane owns one q-row.
__global__ __launch_bounds__(512, 2) void attn_kernel(const _Float16* __restrict__ Q,
                                                      const _Float16* __restrict__ Kg,
                                                      const _Float16* __restrict__ Vt,
                                                      _Float16* __restrict__ ctx) {
  __shared__ char smem[65536]; // [0,32K) K dbuf, [32K,64K) V dbuf; reused for epilogue

  const int tid = threadIdx.x, lane = tid & 63, w = tid >> 6;
  const int l31 = lane & 31, hi = lane >> 5;
  const int bh = blockIdx.x & (BH - 1);
  const int qt = (SEQ / 256) - 1 - (blockIdx.x >> 6); // heavy-first
  const int q0 = qt * 256;
  const int qw = q0 + w * 32;
  const int qrow = qw + l31;       // this lane's q-row
  const int nt = (q0 + 256) / 64;  // 4*(qt+1)

  const char* Kgb = (const char*)(Kg + (size_t)bh * SEQ * DK);
  const char* Vgb = (const char*)(Vt + (size_t)bh * DK * SEQ);

  // Q fragments (B-operand of S^T): lane holds Q[qrow][d = dblk*16 + 8*hi + j], pre-scaled
  half8 qf[8];
  {
    const _Float16* qp = Q + ((size_t)bh * SEQ + qrow) * DK + hi * 8;
    const _Float16 sc = (_Float16)0.08838834764831845f; // 1/sqrt(128)
#pragma unroll
    for (int d = 0; d < 8; ++d) {
      half8 t = *(const half8*)(qp + d * 16);
#pragma unroll
      for (int j = 0; j < 8; ++j) t[j] = t[j] * sc;
      qf[d] = t;
    }
  }

  f32x16 oa[4] = {};
  float m = -3.0e38f, lsum = 0.f;

  auto stage = [&](int t, int buf) {
    char* Kd = smem + buf * 16384;
    char* Vd = smem + 32768 + buf * 16384;
#pragma unroll
    for (int it = 0; it < 2; ++it) {
      int id = it * 512 + tid;
      {
        int row = id >> 4, cc = id & 15;
        int colb = (cc << 4) ^ ((row & 7) << 4);
        gload_lds16(Kgb + (size_t)(t * 64 + row) * 256 + colb, Kd + id * 16);
      }
      {
        int row = id >> 3, cc = id & 7;
        int colb = (cc << 4) ^ ((row & 7) << 4);
        gload_lds16(Vgb + (size_t)row * (SEQ * 2) + (size_t)t * 128 + colb, Vd + id * 16);
      }
    }
  };

  stage(0, 0);
  asm volatile("s_waitcnt vmcnt(0)" ::: "memory");
  __syncthreads();

  int cur = 0;
  for (int t = 0; t < nt; ++t) {
    if (t + 1 < nt) stage(t + 1, cur ^ 1);

    const bool active = (t * 64 <= qw + 31); // wave-uniform
    if (active) {
      const char* Kc = smem + cur * 16384;
      const char* Vc = smem + 32768 + cur * 16384;

      // S^T = K . Q^T  (two 32-key subtiles)
      f32x16 sA = {}, sB = {};
      __builtin_amdgcn_s_setprio(1);
#pragma unroll
      for (int d = 0; d < 8; ++d) {
        int cb = d * 32 + hi * 16;
        half8 kA = *(const half8*)(Kc + l31 * 256 + (cb ^ ((l31 & 7) << 4)));
        half8 kB = *(const half8*)(Kc + (l31 + 32) * 256 + (cb ^ ((l31 & 7) << 4)));
        sA = __builtin_amdgcn_mfma_f32_32x32x16_f16(kA, qf[d], sA, 0, 0, 0);
        sB = __builtin_amdgcn_mfma_f32_32x32x16_f16(kB, qf[d], sB, 0, 0, 0);
      }
      __builtin_amdgcn_s_setprio(0);

      // causal mask (reg r -> k = t*64 + (r&3)+8*(r>>2)+4*hi [+32 for B])
      if (t * 64 + 63 > qw) {
#pragma unroll
        for (int r = 0; r < 16; ++r) {
          int k = t * 64 + (r & 3) + 8 * (r >> 2) + 4 * hi;
          if (k > qrow) sA[r] = -3.0e38f;
          if (k + 32 > qrow) sB[r] = -3.0e38f;
        }
      }

      // row max: in-lane over 32 regs + partner swap
      float tm = -3.0e38f;
#pragma unroll
      for (int r = 0; r < 16; ++r) tm = fmaxf(tm, fmaxf(sA[r], sB[r]));
      tm = fmaxf(tm, __shfl_xor(tm, 32));

      // defer-max (T13): only rescale when some lane's max grew past m+8
      if (__any(tm > m + 8.0f)) {
        float mnew = fmaxf(m, tm);
        float sf = __expf(m - mnew);
        m = mnew;
        lsum *= sf;
#pragma unroll
        for (int db = 0; db < 4; ++db)
#pragma unroll
          for (int r = 0; r < 16; ++r) oa[db][r] *= sf;
      }

      // exp + sum + pack to f16 pairs
      float ps = 0.f;
      unsigned wa[8], wb[8];
#pragma unroll
      for (int i = 0; i < 8; ++i) {
        float a0 = __expf(sA[2 * i] - m), a1 = __expf(sA[2 * i + 1] - m);
        float b0 = __expf(sB[2 * i] - m), b1 = __expf(sB[2 * i + 1] - m);
        ps += a0 + a1 + b0 + b1;
        wa[i] = __builtin_bit_cast(unsigned, __builtin_amdgcn_cvt_pkrtz(a0, a1));
        wb[i] = __builtin_bit_cast(unsigned, __builtin_amdgcn_cvt_pkrtz(b0, b1));
      }
      lsum += ps; // partner halves combined at epilogue

      // build PV B-fragments: one swap fills two output words
      plswap(wa[0], wa[2]); plswap(wa[1], wa[3]); plswap(wa[4], wa[6]); plswap(wa[5], wa[7]);
      plswap(wb[0], wb[2]); plswap(wb[1], wb[3]); plswap(wb[4], wb[6]); plswap(wb[5], wb[7]);

      union { unsigned u[4]; half8 v; } pf[4];
      pf[0].u[0] = wa[0]; pf[0].u[1] = wa[1]; pf[0].u[2] = wa[2]; pf[0].u[3] = wa[3];
      pf[1].u[0] = wa[4]; pf[1].u[1] = wa[5]; pf[1].u[2] = wa[6]; pf[1].u[3] = wa[7];
      pf[2].u[0] = wb[0]; pf[2].u[1] = wb[1]; pf[2].u[2] = wb[2]; pf[2].u[3] = wb[3];
      pf[3].u[0] = wb[4]; pf[3].u[1] = wb[5]; pf[3].u[2] = wb[6]; pf[3].u[3] = wb[7];

      // O^T += Vt . P^T
      __builtin_amdgcn_s_setprio(1);
#pragma unroll
      for (int kg = 0; kg < 4; ++kg) {
#pragma unroll
        for (int db = 0; db < 4; ++db) {
          int row = db * 32 + l31;
          half8 vf = *(const half8*)(Vc + row * 128 + ((kg * 32 + hi * 16) ^ ((row & 7) << 4)));
          oa[db] = __builtin_amdgcn_mfma_f32_32x32x16_f16(vf, pf[kg].v, oa[db], 0, 0, 0);
        }
      }
      __builtin_amdgcn_s_setprio(0);
    }

    asm volatile("s_waitcnt vmcnt(0)" ::: "memory");
    __syncthreads();
    cur ^= 1;
  }

  // epilogue: per-wave LDS transpose then coalesced global stores
  __syncthreads(); // everyone done with K/V LDS
  float lt = lsum + __shfl_xor(lsum, 32);
  float invl = 1.0f / lt;
  char* Ob = smem + w * 8192; // [32 rows][256B]
#pragma unroll
  for (int db = 0; db < 4; ++db)
#pragma unroll
    for (int r = 0; r < 16; ++r) {
      int d = db * 32 + (r & 3) + 8 * (r >> 2) + 4 * hi;
      *(_Float16*)(Ob + l31 * 256 + ((2 * d) ^ ((l31 & 7) << 4))) = (_Float16)(oa[db][r] * invl);
    }
  __builtin_amdgcn_s_waitcnt(0); // lgkmcnt(0) handled by compiler deps; keep ordering
  const int b = bh >> 4, h = bh & 15;
#pragma unroll
  for (int i = 0; i < 8; ++i) {
    int cidx = i * 64 + lane;
    int row = cidx >> 4;
    int colb = (cidx & 15) * 16;
    half8 v = *(const half8*)(Ob + row * 256 + (colb ^ ((row & 7) << 4)));
    int s = qw + row;
    *(half8*)(ctx + ((size_t)(b * SEQ + s)) * D_MODEL + h * DK + colb / 2) = v;
  }
}

// ---------------- launch ----------------
extern "C" void kernel_launch(void* const* d_in, const int* in_sizes, int n_in,
                              void* d_out, int out_size, void* d_ws, size_t ws_size,
                              hipStream_t stream) {
  const float* x = (const float*)d_in[0];
  const int* pos = (const int*)d_in[1];
  const float* Wq = (const float*)d_in[2];
  const float* Wk = (const float*)d_in[3];
  const float* Wv = (const float*)d_in[4];
  const float* Wo = (const float*)d_in[5];
  float* out = (float*)d_out;

  const size_t SZ_XH = (size_t)M_TOT * D_MODEL;
  const size_t SZ_W = (size_t)D_MODEL * D_MODEL;

  _Float16* xh = (_Float16*)d_ws;
  _Float16* wqh = xh + SZ_XH;        // Wq,Wk,Wv,Wo contiguous
  _Float16* woh = wqh + 3 * SZ_W;
  _Float16* Qh = woh + SZ_W;
  _Float16* Kh = Qh + SZ_HEAD;
  _Float16* Vth = Kh + SZ_HEAD;
  _Float16* ctx = xh; // alias: xh dead after QKV GEMM

  cvt_f32_f16<<<2048, 256, 0, stream>>>(x, xh, (int)(SZ_XH / 8));
  cvt4_f32_f16<<<2048, 256, 0, stream>>>(Wq, Wk, Wv, Wo, wqh);

  // fused QKV projection: N = 6144
  gemm_bt<3, true><<<(M_TOT / BM) * (6144 / BN), 256, 0, stream>>>(
      xh, wqh, Qh, pos, M_TOT, 3 * D_MODEL, D_MODEL);

  attn_kernel<<<(SEQ / 256) * BH, 512, 0, stream>>>(Qh, Kh, Vth, ctx);

  gemm_bt<2, false><<<(M_TOT / BM) * (D_MODEL / BN), 256, 0, stream>>>(
      ctx, woh, out, nullptr, M_TOT, D_MODEL, D_MODEL);
}

// Round 4
// 441.647 us; speedup vs baseline: 1.4938x; 1.1323x over previous
//
#include <hip/hip_runtime.h>

#define D_MODEL 2048
#define N_HEADS 16
#define DK 128
#define BATCH 4
#define SEQ 2048
#define BH (BATCH*N_HEADS)   // 64
#define M_TOT (BATCH*SEQ)    // 8192
#define SZ_HEAD ((size_t)BH*SEQ*DK)

typedef _Float16 half8 __attribute__((ext_vector_type(8)));
typedef _Float16 half4 __attribute__((ext_vector_type(4)));
typedef float f32x4 __attribute__((ext_vector_type(4)));
typedef float f32x16 __attribute__((ext_vector_type(16)));

__device__ __forceinline__ void gload_lds16(const void* g, void* l) {
  __builtin_amdgcn_global_load_lds(
      (const __attribute__((address_space(1))) unsigned int*)g,
      (__attribute__((address_space(3))) unsigned int*)l, 16, 0, 0);
}

__device__ __forceinline__ void plswap(unsigned& a, unsigned& b) {
  asm volatile("v_permlane32_swap_b32 %0, %1" : "+v"(a), "+v"(b));
}

// ---------------- converts ----------------
__global__ void cvt_f32_f16(const float* __restrict__ src, _Float16* __restrict__ dst, int n8) {
  int i = blockIdx.x * blockDim.x + threadIdx.x;
  int stride = gridDim.x * blockDim.x;
  for (; i < n8; i += stride) {
    const float4* s = (const float4*)(src + (size_t)i * 8);
    float4 a = s[0], b = s[1];
    half8 h;
    h[0] = (_Float16)a.x; h[1] = (_Float16)a.y; h[2] = (_Float16)a.z; h[3] = (_Float16)a.w;
    h[4] = (_Float16)b.x; h[5] = (_Float16)b.y; h[6] = (_Float16)b.z; h[7] = (_Float16)b.w;
    *(half8*)(dst + (size_t)i * 8) = h;
  }
}

__global__ void cvt4_f32_f16(const float* __restrict__ w0, const float* __restrict__ w1,
                             const float* __restrict__ w2, const float* __restrict__ w3,
                             _Float16* __restrict__ dst) {
  int i = blockIdx.x * blockDim.x + threadIdx.x;
  int stride = gridDim.x * blockDim.x;
  const int total = 4 << 19;
  for (; i < total; i += stride) {
    int which = i >> 19;
    int off = i & ((1 << 19) - 1);
    const float* s = which == 0 ? w0 : which == 1 ? w1 : which == 2 ? w2 : w3;
    const float4* sp = (const float4*)(s + (size_t)off * 8);
    float4 a = sp[0], b = sp[1];
    half8 h;
    h[0] = (_Float16)a.x; h[1] = (_Float16)a.y; h[2] = (_Float16)a.z; h[3] = (_Float16)a.w;
    h[4] = (_Float16)b.x; h[5] = (_Float16)b.y; h[6] = (_Float16)b.z; h[7] = (_Float16)b.w;
    *(half8*)(dst + (size_t)i * 8) = h;
  }
}

// rope table: tab[s*64 + d2] = {cos, sin}
__global__ void build_tab(const int* __restrict__ pos, float2* __restrict__ tab) {
  int i = blockIdx.x * blockDim.x + threadIdx.x; // < SEQ*64
  int s = i >> 6, d2 = i & 63;
  float inv = exp2f(-(float)d2 * (13.287712379549449f / 64.0f));
  float ang = (float)pos[s] * inv;
  tab[i] = make_float2(__cosf(ang), __sinf(ang));
}

// ---------------- 256x256 8-phase GEMM: C = A @ Bt^T ----------------
// EPI: 2 = f32 row-major out; 3 = fused QKV (Q/K roped heads via tab, V transposed)
template <int EPI>
__global__ __launch_bounds__(512, 2) void gemm8p(const _Float16* __restrict__ A,
                                                 const _Float16* __restrict__ Bt,
                                                 void* __restrict__ Cout,
                                                 const float2* __restrict__ tab,
                                                 int N, int K) {
  __shared__ char lds[131072]; // A: 4 slots @0, B: 4 slots @65536; slot = 16KB (256 rows x 64B)

  const int tid = threadIdx.x;
  const int lane = tid & 63;
  const int w = tid >> 6;
  const int wr = w >> 2, wc = w & 3;
  const int lr = lane & 15, lg = lane >> 4;

  // XCD-bijective swizzle (grid % 8 == 0 always here), B-panel-resident decomposition
  const int nwg = gridDim.x;
  const int cpx = nwg >> 3;
  const int wgid = (blockIdx.x & 7) * cpx + (blockIdx.x >> 3);
  const int nby = M_TOT / 256;
  const int by = wgid % nby, bx = wgid / nby;
  const int m0 = by * 256, n0 = bx * 256;

  const int T = K >> 6; // K-tiles of 64
  const size_t Kb = (size_t)K * 2;
  const char* Ab = (const char*)A + (size_t)m0 * Kb;
  const char* Bb = (const char*)Bt + (size_t)n0 * Kb;

  f32x4 acc[8][4] = {};

  // stage one k-half (256 rows x 32 f16) of tile t into its slot
  auto stageHalf = [&](int t, int kh, bool isB) {
    char* dst = lds + (isB ? 65536 : 0) + (((t & 1) << 1) + kh) * 16384;
    const char* src = isB ? Bb : Ab;
    int kbyte = t * 128 + kh * 64;
#pragma unroll
    for (int it = 0; it < 2; ++it) {
      int id = it * 512 + tid;
      int o = id * 16;
      int row = o >> 6;
      int c16 = (o >> 4) & 3;
      gload_lds16(src + (size_t)row * Kb + kbyte + (((c16 ^ (row & 3)) << 4)), dst + o);
    }
  };
  auto readA = [&](int par, int m, int ks) -> half8 {
    int row = wr * 128 + m * 16 + lr;
    return *(const half8*)(lds + ((par << 1) + ks) * 16384 + row * 64 + ((lg * 16) ^ ((row & 3) << 4)));
  };
  auto readB = [&](int par, int n, int ks) -> half8 {
    int row = wc * 64 + n * 16 + lr;
    return *(const half8*)(lds + 65536 + ((par << 1) + ks) * 16384 + row * 64 + ((lg * 16) ^ ((row & 3) << 4)));
  };

  // prologue: t0 both halves + t1 k0
  stageHalf(0, 0, false); stageHalf(0, 0, true);
  stageHalf(0, 1, false); stageHalf(0, 1, true);
  stageHalf(1, 0, false); stageHalf(1, 0, true);
  asm volatile("s_waitcnt vmcnt(4)" ::: "memory");
  __builtin_amdgcn_s_barrier();
  asm volatile("" ::: "memory");

  for (int t = 0; t < T; ++t) {
    const int par = t & 1;
    half8 aF[4], bF[4];

    // ---- phase 0: ks0, m 0-3 ----
    if (t + 1 < T) stageHalf(t + 1, 1, false);
#pragma unroll
    for (int n = 0; n < 4; ++n) bF[n] = readB(par, n, 0);
#pragma unroll
    for (int m = 0; m < 4; ++m) aF[m] = readA(par, m, 0);
    __builtin_amdgcn_s_setprio(1);
#pragma unroll
    for (int m = 0; m < 4; ++m)
#pragma unroll
      for (int n = 0; n < 4; ++n)
        acc[m][n] = __builtin_amdgcn_mfma_f32_16x16x32_f16(aF[m], bF[n], acc[m][n], 0, 0, 0);
    __builtin_amdgcn_s_setprio(0);
    asm volatile("" ::: "memory");
    __builtin_amdgcn_s_barrier();
    asm volatile("" ::: "memory");

    // ---- phase 1: ks0, m 4-7 ----
    if (t + 1 < T) stageHalf(t + 1, 1, true);
#pragma unroll
    for (int m = 0; m < 4; ++m) aF[m] = readA(par, 4 + m, 0);
    __builtin_amdgcn_s_setprio(1);
#pragma unroll
    for (int m = 0; m < 4; ++m)
#pragma unroll
      for (int n = 0; n < 4; ++n)
        acc[4 + m][n] = __builtin_amdgcn_mfma_f32_16x16x32_f16(aF[m], bF[n], acc[4 + m][n], 0, 0, 0);
    __builtin_amdgcn_s_setprio(0);
    asm volatile("" ::: "memory");
    __builtin_amdgcn_s_barrier();
    asm volatile("" ::: "memory");

    // ---- phase 2: ks1, m 0-3 ----
    if (t + 2 < T) stageHalf(t + 2, 0, false);
#pragma unroll
    for (int n = 0; n < 4; ++n) bF[n] = readB(par, n, 1);
#pragma unroll
    for (int m = 0; m < 4; ++m) aF[m] = readA(par, m, 1);
    __builtin_amdgcn_s_setprio(1);
#pragma unroll
    for (int m = 0; m < 4; ++m)
#pragma unroll
      for (int n = 0; n < 4; ++n)
        acc[m][n] = __builtin_amdgcn_mfma_f32_16x16x32_f16(aF[m], bF[n], acc[m][n], 0, 0, 0);
    __builtin_amdgcn_s_setprio(0);
    asm volatile("" ::: "memory");
    __builtin_amdgcn_s_barrier();
    asm volatile("" ::: "memory");

    // ---- phase 3: ks1, m 4-7 ----
    if (t + 2 < T) stageHalf(t + 2, 0, true);
#pragma unroll
    for (int m = 0; m < 4; ++m) aF[m] = readA(par, 4 + m, 1);
    __builtin_amdgcn_s_setprio(1);
#pragma unroll
    for (int m = 0; m < 4; ++m)
#pragma unroll
      for (int n = 0; n < 4; ++n)
        acc[4 + m][n] = __builtin_amdgcn_mfma_f32_16x16x32_f16(aF[m], bF[n], acc[4 + m][n], 0, 0, 0);
    __builtin_amdgcn_s_setprio(0);

    // ---- tile boundary: counted vmcnt, never drain mid-stream ----
    if (t + 1 < T) {
      if (t + 2 < T) {
        asm volatile("s_waitcnt vmcnt(4)" ::: "memory");
      } else {
        asm volatile("s_waitcnt vmcnt(0)" ::: "memory");
      }
      __builtin_amdgcn_s_barrier();
      asm volatile("" ::: "memory");
    }
  }

  // ---------------- epilogue ----------------
  if (EPI == 3) {
    const int which = n0 >> 11; // 0=Q,1=K,2=V
#pragma unroll
    for (int mf = 0; mf < 8; ++mf) {
      int row0 = m0 + wr * 128 + mf * 16 + lg * 4;
      int b = row0 >> 11;
#pragma unroll
      for (int nf = 0; nf < 4; ++nf) {
        int col = n0 + wc * 64 + nf * 16 + lr;
        int h = (col >> 7) & 15, d = col & 127;
        if (which < 2) {
          _Float16* O = (_Float16*)Cout + (size_t)which * SZ_HEAD;
          int d2 = d >> 1;
#pragma unroll
          for (int r = 0; r < 4; ++r) {
            int s = (row0 + r) & (SEQ - 1);
            float2 cs = tab[(s << 6) + d2];
            float v = acc[mf][nf][r];
            float p = __shfl_xor(v, 1);
            v = (lr & 1) ? fmaf(v, cs.x, p * cs.y) : fmaf(v, cs.x, -p * cs.y);
            O[((size_t)(b * N_HEADS + h) * SEQ + s) * DK + d] = (_Float16)v;
          }
        } else {
          _Float16* O = (_Float16*)Cout + 2 * SZ_HEAD;
          int s = row0 & (SEQ - 1);
          half4 v;
          v[0] = (_Float16)acc[mf][nf][0]; v[1] = (_Float16)acc[mf][nf][1];
          v[2] = (_Float16)acc[mf][nf][2]; v[3] = (_Float16)acc[mf][nf][3];
          *(half4*)&O[((size_t)(b * N_HEADS + h) * DK + d) * SEQ + s] = v;
        }
      }
    }
  } else {
    float* O = (float*)Cout;
#pragma unroll
    for (int mf = 0; mf < 8; ++mf) {
      int row0 = m0 + wr * 128 + mf * 16 + lg * 4;
#pragma unroll
      for (int nf = 0; nf < 4; ++nf) {
        int col = n0 + wc * 64 + nf * 16 + lr;
#pragma unroll
        for (int r = 0; r < 4; ++r)
          O[(size_t)(row0 + r) * N + col] = acc[mf][nf][r];
      }
    }
  }
}

// ---------------- causal flash attention (swapped-operand 32x32) ----------------
__global__ __launch_bounds__(512, 2) void attn_kernel(const _Float16* __restrict__ Q,
                                                      const _Float16* __restrict__ Kg,
                                                      const _Float16* __restrict__ Vt,
                                                      _Float16* __restrict__ ctx) {
  __shared__ char smem[65536];

  const int tid = threadIdx.x, lane = tid & 63, w = tid >> 6;
  const int l31 = lane & 31, hi = lane >> 5;
  const int bh = blockIdx.x & (BH - 1);
  const int qt = (SEQ / 256) - 1 - (blockIdx.x >> 6); // heavy-first
  const int q0 = qt * 256;
  const int qw = q0 + w * 32;
  const int qrow = qw + l31;
  const int nt = (q0 + 256) / 64;

  const char* Kgb = (const char*)(Kg + (size_t)bh * SEQ * DK);
  const char* Vgb = (const char*)(Vt + (size_t)bh * DK * SEQ);

  half8 qf[8];
  {
    const _Float16* qp = Q + ((size_t)bh * SEQ + qrow) * DK + hi * 8;
    const _Float16 sc = (_Float16)0.08838834764831845f;
#pragma unroll
    for (int d = 0; d < 8; ++d) {
      half8 t = *(const half8*)(qp + d * 16);
#pragma unroll
      for (int j = 0; j < 8; ++j) t[j] = t[j] * sc;
      qf[d] = t;
    }
  }

  f32x16 oa[4] = {};
  float m = -3.0e38f, lsum = 0.f;

  auto stage = [&](int t, int buf) {
    char* Kd = smem + buf * 16384;
    char* Vd = smem + 32768 + buf * 16384;
#pragma unroll
    for (int it = 0; it < 2; ++it) {
      int id = it * 512 + tid;
      {
        int row = id >> 4, cc = id & 15;
        int colb = (cc << 4) ^ ((row & 7) << 4);
        gload_lds16(Kgb + (size_t)(t * 64 + row) * 256 + colb, Kd + id * 16);
      }
      {
        int row = id >> 3, cc = id & 7;
        int colb = (cc << 4) ^ ((row & 7) << 4);
        gload_lds16(Vgb + (size_t)row * (SEQ * 2) + (size_t)t * 128 + colb, Vd + id * 16);
      }
    }
  };

  stage(0, 0);
  asm volatile("s_waitcnt vmcnt(0)" ::: "memory");
  __syncthreads();

  int cur = 0;
  for (int t = 0; t < nt; ++t) {
    if (t + 1 < nt) stage(t + 1, cur ^ 1);

    const bool active = (t * 64 <= qw + 31);
    if (active) {
      const char* Kc = smem + cur * 16384;
      const char* Vc = smem + 32768 + cur * 16384;

      f32x16 sA = {}, sB = {};
      __builtin_amdgcn_s_setprio(1);
#pragma unroll
      for (int d = 0; d < 8; ++d) {
        int cb = d * 32 + hi * 16;
        half8 kA = *(const half8*)(Kc + l31 * 256 + (cb ^ ((l31 & 7) << 4)));
        half8 kB = *(const half8*)(Kc + (l31 + 32) * 256 + (cb ^ ((l31 & 7) << 4)));
        sA = __builtin_amdgcn_mfma_f32_32x32x16_f16(kA, qf[d], sA, 0, 0, 0);
        sB = __builtin_amdgcn_mfma_f32_32x32x16_f16(kB, qf[d], sB, 0, 0, 0);
      }
      __builtin_amdgcn_s_setprio(0);

      if (t * 64 + 63 > qw) {
#pragma unroll
        for (int r = 0; r < 16; ++r) {
          int k = t * 64 + (r & 3) + 8 * (r >> 2) + 4 * hi;
          if (k > qrow) sA[r] = -3.0e38f;
          if (k + 32 > qrow) sB[r] = -3.0e38f;
        }
      }

      float tm = -3.0e38f;
#pragma unroll
      for (int r = 0; r < 16; ++r) tm = fmaxf(tm, fmaxf(sA[r], sB[r]));
      tm = fmaxf(tm, __shfl_xor(tm, 32));

      if (__any(tm > m + 8.0f)) {
        float mnew = fmaxf(m, tm);
        float sf = __expf(m - mnew);
        m = mnew;
        lsum *= sf;
#pragma unroll
        for (int db = 0; db < 4; ++db)
#pragma unroll
          for (int r = 0; r < 16; ++r) oa[db][r] *= sf;
      }

      float ps = 0.f;
      unsigned wa[8], wb[8];
#pragma unroll
      for (int i = 0; i < 8; ++i) {
        float a0 = __expf(sA[2 * i] - m), a1 = __expf(sA[2 * i + 1] - m);
        float b0 = __expf(sB[2 * i] - m), b1 = __expf(sB[2 * i + 1] - m);
        ps += a0 + a1 + b0 + b1;
        wa[i] = __builtin_bit_cast(unsigned, __builtin_amdgcn_cvt_pkrtz(a0, a1));
        wb[i] = __builtin_bit_cast(unsigned, __builtin_amdgcn_cvt_pkrtz(b0, b1));
      }
      lsum += ps;

      plswap(wa[0], wa[2]); plswap(wa[1], wa[3]); plswap(wa[4], wa[6]); plswap(wa[5], wa[7]);
      plswap(wb[0], wb[2]); plswap(wb[1], wb[3]); plswap(wb[4], wb[6]); plswap(wb[5], wb[7]);

      union { unsigned u[4]; half8 v; } pf[4];
      pf[0].u[0] = wa[0]; pf[0].u[1] = wa[1]; pf[0].u[2] = wa[2]; pf[0].u[3] = wa[3];
      pf[1].u[0] = wa[4]; pf[1].u[1] = wa[5]; pf[1].u[2] = wa[6]; pf[1].u[3] = wa[7];
      pf[2].u[0] = wb[0]; pf[2].u[1] = wb[1]; pf[2].u[2] = wb[2]; pf[2].u[3] = wb[3];
      pf[3].u[0] = wb[4]; pf[3].u[1] = wb[5]; pf[3].u[2] = wb[6]; pf[3].u[3] = wb[7];

      __builtin_amdgcn_s_setprio(1);
#pragma unroll
      for (int kg = 0; kg < 4; ++kg) {
#pragma unroll
        for (int db = 0; db < 4; ++db) {
          int row = db * 32 + l31;
          half8 vf = *(const half8*)(Vc + row * 128 + ((kg * 32 + hi * 16) ^ ((row & 7) << 4)));
          oa[db] = __builtin_amdgcn_mfma_f32_32x32x16_f16(vf, pf[kg].v, oa[db], 0, 0, 0);
        }
      }
      __builtin_amdgcn_s_setprio(0);
    }

    asm volatile("s_waitcnt vmcnt(0)" ::: "memory");
    __syncthreads();
    cur ^= 1;
  }

  __syncthreads();
  float lt = lsum + __shfl_xor(lsum, 32);
  float invl = 1.0f / lt;
  char* Ob = smem + w * 8192;
#pragma unroll
  for (int db = 0; db < 4; ++db)
#pragma unroll
    for (int r = 0; r < 16; ++r) {
      int d = db * 32 + (r & 3) + 8 * (r >> 2) + 4 * hi;
      *(_Float16*)(Ob + l31 * 256 + ((2 * d) ^ ((l31 & 7) << 4))) = (_Float16)(oa[db][r] * invl);
    }
  __builtin_amdgcn_s_waitcnt(0);
  const int b = bh >> 4, h = bh & 15;
#pragma unroll
  for (int i = 0; i < 8; ++i) {
    int cidx = i * 64 + lane;
    int row = cidx >> 4;
    int colb = (cidx & 15) * 16;
    half8 v = *(const half8*)(Ob + row * 256 + (colb ^ ((row & 7) << 4)));
    int s = qw + row;
    *(half8*)(ctx + ((size_t)(b * SEQ + s)) * D_MODEL + h * DK + colb / 2) = v;
  }
}

// ---------------- launch ----------------
extern "C" void kernel_launch(void* const* d_in, const int* in_sizes, int n_in,
                              void* d_out, int out_size, void* d_ws, size_t ws_size,
                              hipStream_t stream) {
  const float* x = (const float*)d_in[0];
  const int* pos = (const int*)d_in[1];
  const float* Wq = (const float*)d_in[2];
  const float* Wk = (const float*)d_in[3];
  const float* Wv = (const float*)d_in[4];
  const float* Wo = (const float*)d_in[5];
  float* out = (float*)d_out;

  const size_t SZ_XH = (size_t)M_TOT * D_MODEL;
  const size_t SZ_W = (size_t)D_MODEL * D_MODEL;

  _Float16* xh = (_Float16*)d_ws;
  _Float16* wqh = xh + SZ_XH;        // Wq,Wk,Wv,Wo contiguous
  _Float16* woh = wqh + 3 * SZ_W;
  _Float16* Qh = woh + SZ_W;
  _Float16* Kh = Qh + SZ_HEAD;
  _Float16* Vth = Kh + SZ_HEAD;
  _Float16* ctx = xh;                 // alias: xh dead after QKV GEMM
  float2* tab = (float2*)d_out;       // first 1MB of out; fully overwritten by O-GEMM

  cvt_f32_f16<<<2048, 256, 0, stream>>>(x, xh, (int)(SZ_XH / 8));
  cvt4_f32_f16<<<2048, 256, 0, stream>>>(Wq, Wk, Wv, Wo, wqh);
  build_tab<<<SEQ * 64 / 256, 256, 0, stream>>>(pos, tab);

  // fused QKV projection: N = 6144, 256x256 tiles -> 32x24 = 768 blocks
  gemm8p<3><<<768, 512, 0, stream>>>(xh, wqh, Qh, tab, 3 * D_MODEL, D_MODEL);

  attn_kernel<<<(SEQ / 256) * BH, 512, 0, stream>>>(Qh, Kh, Vth, ctx);

  // output projection: 32x8 = 256 blocks
  gemm8p<2><<<256, 512, 0, stream>>>(ctx, woh, out, nullptr, D_MODEL, D_MODEL);
}

// Round 5
// 420.669 us; speedup vs baseline: 1.5683x; 1.0499x over previous
//
#include <hip/hip_runtime.h>

#define D_MODEL 2048
#define N_HEADS 16
#define DK 128
#define BATCH 4
#define SEQ 2048
#define BH (BATCH*N_HEADS)   // 64
#define M_TOT (BATCH*SEQ)    // 8192
#define SZ_HEAD ((size_t)BH*SEQ*DK)

typedef _Float16 half8 __attribute__((ext_vector_type(8)));
typedef _Float16 half4 __attribute__((ext_vector_type(4)));
typedef float f32x4 __attribute__((ext_vector_type(4)));
typedef float f32x16 __attribute__((ext_vector_type(16)));

__device__ __forceinline__ void gload_lds16(const void* g, void* l) {
  __builtin_amdgcn_global_load_lds(
      (const __attribute__((address_space(1))) unsigned int*)g,
      (__attribute__((address_space(3))) unsigned int*)l, 16, 0, 0);
}

__device__ __forceinline__ void plswap(unsigned& a, unsigned& b) {
  asm volatile("v_permlane32_swap_b32 %0, %1" : "+v"(a), "+v"(b));
}

// ---------------- converts ----------------
__global__ void cvt_f32_f16(const float* __restrict__ src, _Float16* __restrict__ dst, int n8) {
  int i = blockIdx.x * blockDim.x + threadIdx.x;
  int stride = gridDim.x * blockDim.x;
  for (; i < n8; i += stride) {
    const float4* s = (const float4*)(src + (size_t)i * 8);
    float4 a = s[0], b = s[1];
    half8 h;
    h[0] = (_Float16)a.x; h[1] = (_Float16)a.y; h[2] = (_Float16)a.z; h[3] = (_Float16)a.w;
    h[4] = (_Float16)b.x; h[5] = (_Float16)b.y; h[6] = (_Float16)b.z; h[7] = (_Float16)b.w;
    *(half8*)(dst + (size_t)i * 8) = h;
  }
}

__global__ void cvt4_f32_f16(const float* __restrict__ w0, const float* __restrict__ w1,
                             const float* __restrict__ w2, const float* __restrict__ w3,
                             _Float16* __restrict__ dst) {
  int i = blockIdx.x * blockDim.x + threadIdx.x;
  int stride = gridDim.x * blockDim.x;
  const int total = 4 << 19;
  for (; i < total; i += stride) {
    int which = i >> 19;
    int off = i & ((1 << 19) - 1);
    const float* s = which == 0 ? w0 : which == 1 ? w1 : which == 2 ? w2 : w3;
    const float4* sp = (const float4*)(s + (size_t)off * 8);
    float4 a = sp[0], b = sp[1];
    half8 h;
    h[0] = (_Float16)a.x; h[1] = (_Float16)a.y; h[2] = (_Float16)a.z; h[3] = (_Float16)a.w;
    h[4] = (_Float16)b.x; h[5] = (_Float16)b.y; h[6] = (_Float16)b.z; h[7] = (_Float16)b.w;
    *(half8*)(dst + (size_t)i * 8) = h;
  }
}

// rope table: tab[s*64 + d2] = {cos, sin}
__global__ void build_tab(const int* __restrict__ pos, float2* __restrict__ tab) {
  int i = blockIdx.x * blockDim.x + threadIdx.x; // < SEQ*64
  int s = i >> 6, d2 = i & 63;
  float inv = exp2f(-(float)d2 * (13.287712379549449f / 64.0f));
  float ang = (float)pos[s] * inv;
  tab[i] = make_float2(__cosf(ang), __sinf(ang));
}

// ---------------- 256x256 8-phase GEMM: C = A @ Bt^T ----------------
// LDS slots: 128-row halves (M/N-split), 128B rows, 3-bit XOR swizzle -> conflict-free.
// EPI: 2 = f32 row-major out; 3 = fused QKV (Q/K roped heads via tab, V transposed)
template <int EPI>
__global__ __launch_bounds__(512, 2) void gemm8p(const _Float16* __restrict__ A,
                                                 const _Float16* __restrict__ Bt,
                                                 void* __restrict__ Cout,
                                                 const float2* __restrict__ tab,
                                                 int N, int K) {
  __shared__ char lds[131072]; // A: 4 slots @0, B: 4 slots @65536; slot = 16KB (128 rows x 128B)

  const int tid = threadIdx.x;
  const int lane = tid & 63;
  const int w = tid >> 6;
  const int wr = w >> 2, wc = w & 3;
  const int lr = lane & 15, lg = lane >> 4;

  // XCD-bijective swizzle (grid % 8 == 0 here), B-panel-resident decomposition
  const int nwg = gridDim.x;
  const int cpx = nwg >> 3;
  const int wgid = (blockIdx.x & 7) * cpx + (blockIdx.x >> 3);
  const int nby = M_TOT / 256;
  const int by = wgid % nby, bx = wgid / nby;
  const int m0 = by * 256, n0 = bx * 256;

  const int T = K >> 6;
  const size_t Kb = (size_t)K * 2;
  const char* Ab = (const char*)A + (size_t)m0 * Kb;
  const char* Bb = (const char*)Bt + (size_t)n0 * Kb;

  f32x4 acc[8][4] = {};

  // stage one 128-row half of tile t: 128 rows x 128B, pre-swizzled source
  auto stageHalf = [&](int t, int half, bool isB) {
    char* dst = lds + (isB ? 65536 : 0) + (((t & 1) << 1) + half) * 16384;
    const char* src = (isB ? Bb : Ab) + (size_t)(half * 128) * Kb + t * 128;
#pragma unroll
    for (int it = 0; it < 2; ++it) {
      int id = it * 512 + tid;
      int o = id * 16;
      int rl = o >> 7;          // 0..127
      int blk = (o >> 4) & 7;
      gload_lds16(src + (size_t)rl * Kb + ((blk ^ (rl & 7)) << 4), dst + o);
    }
  };
  auto readA = [&](int par, int m, int ks) -> half8 {
    int rl = m * 16 + lr;
    return *(const half8*)(lds + ((par << 1) + wr) * 16384 + rl * 128 +
                           ((ks * 64 + lg * 16) ^ ((rl & 7) << 4)));
  };
  auto readB = [&](int par, int n, int ks) -> half8 {
    int rl = (wc & 1) * 64 + n * 16 + lr;
    return *(const half8*)(lds + 65536 + ((par << 1) + (wc >> 1)) * 16384 + rl * 128 +
                           ((ks * 64 + lg * 16) ^ ((rl & 7) << 4)));
  };

  // prologue: tile 0, all 4 halves
  stageHalf(0, 0, false); stageHalf(0, 1, false);
  stageHalf(0, 0, true);  stageHalf(0, 1, true);
  asm volatile("s_waitcnt vmcnt(0)" ::: "memory");
  __builtin_amdgcn_s_barrier();
  asm volatile("" ::: "memory");

  for (int t = 0; t < T; ++t) {
    const int par = t & 1;
    half8 aF[4], bF[4];

    // ---- phase 0: ks0, m 0-3 (stage t+1 A halves -> par^1 slots, not read this tile) ----
    if (t + 1 < T) { stageHalf(t + 1, 0, false); stageHalf(t + 1, 1, false); }
#pragma unroll
    for (int n = 0; n < 4; ++n) bF[n] = readB(par, n, 0);
#pragma unroll
    for (int m = 0; m < 4; ++m) aF[m] = readA(par, m, 0);
    __builtin_amdgcn_s_setprio(1);
#pragma unroll
    for (int m = 0; m < 4; ++m)
#pragma unroll
      for (int n = 0; n < 4; ++n)
        acc[m][n] = __builtin_amdgcn_mfma_f32_16x16x32_f16(aF[m], bF[n], acc[m][n], 0, 0, 0);
    __builtin_amdgcn_s_setprio(0);
    asm volatile("" ::: "memory");
    __builtin_amdgcn_s_barrier();
    asm volatile("" ::: "memory");

    // ---- phase 1: ks0, m 4-7 (stage t+1 B halves) ----
    if (t + 1 < T) { stageHalf(t + 1, 0, true); stageHalf(t + 1, 1, true); }
#pragma unroll
    for (int m = 0; m < 4; ++m) aF[m] = readA(par, 4 + m, 0);
    __builtin_amdgcn_s_setprio(1);
#pragma unroll
    for (int m = 0; m < 4; ++m)
#pragma unroll
      for (int n = 0; n < 4; ++n)
        acc[4 + m][n] = __builtin_amdgcn_mfma_f32_16x16x32_f16(aF[m], bF[n], acc[4 + m][n], 0, 0, 0);
    __builtin_amdgcn_s_setprio(0);
    asm volatile("" ::: "memory");
    __builtin_amdgcn_s_barrier();
    asm volatile("" ::: "memory");

    // ---- phase 2: ks1, m 0-3 ----
#pragma unroll
    for (int n = 0; n < 4; ++n) bF[n] = readB(par, n, 1);
#pragma unroll
    for (int m = 0; m < 4; ++m) aF[m] = readA(par, m, 1);
    __builtin_amdgcn_s_setprio(1);
#pragma unroll
    for (int m = 0; m < 4; ++m)
#pragma unroll
      for (int n = 0; n < 4; ++n)
        acc[m][n] = __builtin_amdgcn_mfma_f32_16x16x32_f16(aF[m], bF[n], acc[m][n], 0, 0, 0);
    __builtin_amdgcn_s_setprio(0);
    asm volatile("" ::: "memory");
    __builtin_amdgcn_s_barrier();
    asm volatile("" ::: "memory");

    // ---- phase 3: ks1, m 4-7 ----
#pragma unroll
    for (int m = 0; m < 4; ++m) aF[m] = readA(par, 4 + m, 1);
    __builtin_amdgcn_s_setprio(1);
#pragma unroll
    for (int m = 0; m < 4; ++m)
#pragma unroll
      for (int n = 0; n < 4; ++n)
        acc[4 + m][n] = __builtin_amdgcn_mfma_f32_16x16x32_f16(aF[m], bF[n], acc[4 + m][n], 0, 0, 0);
    __builtin_amdgcn_s_setprio(0);

    // ---- tile boundary: drain staging (issued >=3 phases ago -> latency-covered) ----
    asm volatile("s_waitcnt vmcnt(0)" ::: "memory");
    __builtin_amdgcn_s_barrier();
    asm volatile("" ::: "memory");
  }

  // ---------------- epilogue ----------------
  if (EPI == 3) {
    const int which = n0 >> 11; // 0=Q,1=K,2=V
#pragma unroll
    for (int mf = 0; mf < 8; ++mf) {
      int row0 = m0 + wr * 128 + mf * 16 + lg * 4;
      int b = row0 >> 11;
#pragma unroll
      for (int nf = 0; nf < 4; ++nf) {
        int col = n0 + wc * 64 + nf * 16 + lr;
        int h = (col >> 7) & 15, d = col & 127;
        if (which < 2) {
          _Float16* O = (_Float16*)Cout + (size_t)which * SZ_HEAD;
          int d2 = d >> 1;
#pragma unroll
          for (int r = 0; r < 4; ++r) {
            int s = (row0 + r) & (SEQ - 1);
            float2 cs = tab[(s << 6) + d2];
            float v = acc[mf][nf][r];
            float p = __shfl_xor(v, 1);
            v = (lr & 1) ? fmaf(v, cs.x, p * cs.y) : fmaf(v, cs.x, -p * cs.y);
            O[((size_t)(b * N_HEADS + h) * SEQ + s) * DK + d] = (_Float16)v;
          }
        } else {
          _Float16* O = (_Float16*)Cout + 2 * SZ_HEAD;
          int s = row0 & (SEQ - 1);
          half4 v;
          v[0] = (_Float16)acc[mf][nf][0]; v[1] = (_Float16)acc[mf][nf][1];
          v[2] = (_Float16)acc[mf][nf][2]; v[3] = (_Float16)acc[mf][nf][3];
          *(half4*)&O[((size_t)(b * N_HEADS + h) * DK + d) * SEQ + s] = v;
        }
      }
    }
  } else {
    float* O = (float*)Cout;
#pragma unroll
    for (int mf = 0; mf < 8; ++mf) {
      int row0 = m0 + wr * 128 + mf * 16 + lg * 4;
#pragma unroll
      for (int nf = 0; nf < 4; ++nf) {
        int col = n0 + wc * 64 + nf * 16 + lr;
#pragma unroll
        for (int r = 0; r < 4; ++r)
          O[(size_t)(row0 + r) * N + col] = acc[mf][nf][r];
      }
    }
  }
}

// ---------------- causal flash attention (swapped-operand 32x32) ----------------
__global__ __launch_bounds__(512, 2) void attn_kernel(const _Float16* __restrict__ Q,
                                                      const _Float16* __restrict__ Kg,
                                                      const _Float16* __restrict__ Vt,
                                                      _Float16* __restrict__ ctx) {
  __shared__ char smem[65536];

  const int tid = threadIdx.x, lane = tid & 63, w = tid >> 6;
  const int l31 = lane & 31, hi = lane >> 5;
  const int bh = blockIdx.x & (BH - 1);
  const int qt = (SEQ / 256) - 1 - (blockIdx.x >> 6); // heavy-first
  const int q0 = qt * 256;
  const int qw = q0 + w * 32;
  const int qrow = qw + l31;
  const int nt = (q0 + 256) / 64;

  const char* Kgb = (const char*)(Kg + (size_t)bh * SEQ * DK);
  const char* Vgb = (const char*)(Vt + (size_t)bh * DK * SEQ);

  half8 qf[8];
  {
    const _Float16* qp = Q + ((size_t)bh * SEQ + qrow) * DK + hi * 8;
    const _Float16 sc = (_Float16)0.08838834764831845f;
#pragma unroll
    for (int d = 0; d < 8; ++d) {
      half8 t = *(const half8*)(qp + d * 16);
#pragma unroll
      for (int j = 0; j < 8; ++j) t[j] = t[j] * sc;
      qf[d] = t;
    }
  }

  f32x16 oa[4] = {};
  float m = -3.0e38f, lsum = 0.f;

  auto stage = [&](int t, int buf) {
    char* Kd = smem + buf * 16384;
    char* Vd = smem + 32768 + buf * 16384;
#pragma unroll
    for (int it = 0; it < 2; ++it) {
      int id = it * 512 + tid;
      {
        int row = id >> 4, cc = id & 15;
        int colb = (cc << 4) ^ ((row & 7) << 4);
        gload_lds16(Kgb + (size_t)(t * 64 + row) * 256 + colb, Kd + id * 16);
      }
      {
        int row = id >> 3, cc = id & 7;
        int colb = (cc << 4) ^ ((row & 7) << 4);
        gload_lds16(Vgb + (size_t)row * (SEQ * 2) + (size_t)t * 128 + colb, Vd + id * 16);
      }
    }
  };

  stage(0, 0);
  asm volatile("s_waitcnt vmcnt(0)" ::: "memory");
  __syncthreads();

  int cur = 0;
  for (int t = 0; t < nt; ++t) {
    if (t + 1 < nt) stage(t + 1, cur ^ 1);

    const bool active = (t * 64 <= qw + 31);
    if (active) {
      const char* Kc = smem + cur * 16384;
      const char* Vc = smem + 32768 + cur * 16384;

      f32x16 sA = {}, sB = {};
      __builtin_amdgcn_s_setprio(1);
#pragma unroll
      for (int d = 0; d < 8; ++d) {
        int cb = d * 32 + hi * 16;
        half8 kA = *(const half8*)(Kc + l31 * 256 + (cb ^ ((l31 & 7) << 4)));
        half8 kB = *(const half8*)(Kc + (l31 + 32) * 256 + (cb ^ ((l31 & 7) << 4)));
        sA = __builtin_amdgcn_mfma_f32_32x32x16_f16(kA, qf[d], sA, 0, 0, 0);
        sB = __builtin_amdgcn_mfma_f32_32x32x16_f16(kB, qf[d], sB, 0, 0, 0);
      }
      __builtin_amdgcn_s_setprio(0);

      if (t * 64 + 63 > qw) {
#pragma unroll
        for (int r = 0; r < 16; ++r) {
          int k = t * 64 + (r & 3) + 8 * (r >> 2) + 4 * hi;
          if (k > qrow) sA[r] = -3.0e38f;
          if (k + 32 > qrow) sB[r] = -3.0e38f;
        }
      }

      float tm = -3.0e38f;
#pragma unroll
      for (int r = 0; r < 16; ++r) tm = fmaxf(tm, fmaxf(sA[r], sB[r]));
      tm = fmaxf(tm, __shfl_xor(tm, 32));

      if (__any(tm > m + 8.0f)) {
        float mnew = fmaxf(m, tm);
        float sf = __expf(m - mnew);
        m = mnew;
        lsum *= sf;
#pragma unroll
        for (int db = 0; db < 4; ++db)
#pragma unroll
          for (int r = 0; r < 16; ++r) oa[db][r] *= sf;
      }

      float ps = 0.f;
      unsigned wa[8], wb[8];
#pragma unroll
      for (int i = 0; i < 8; ++i) {
        float a0 = __expf(sA[2 * i] - m), a1 = __expf(sA[2 * i + 1] - m);
        float b0 = __expf(sB[2 * i] - m), b1 = __expf(sB[2 * i + 1] - m);
        ps += a0 + a1 + b0 + b1;
        wa[i] = __builtin_bit_cast(unsigned, __builtin_amdgcn_cvt_pkrtz(a0, a1));
        wb[i] = __builtin_bit_cast(unsigned, __builtin_amdgcn_cvt_pkrtz(b0, b1));
      }
      lsum += ps;

      plswap(wa[0], wa[2]); plswap(wa[1], wa[3]); plswap(wa[4], wa[6]); plswap(wa[5], wa[7]);
      plswap(wb[0], wb[2]); plswap(wb[1], wb[3]); plswap(wb[4], wb[6]); plswap(wb[5], wb[7]);

      union { unsigned u[4]; half8 v; } pf[4];
      pf[0].u[0] = wa[0]; pf[0].u[1] = wa[1]; pf[0].u[2] = wa[2]; pf[0].u[3] = wa[3];
      pf[1].u[0] = wa[4]; pf[1].u[1] = wa[5]; pf[1].u[2] = wa[6]; pf[1].u[3] = wa[7];
      pf[2].u[0] = wb[0]; pf[2].u[1] = wb[1]; pf[2].u[2] = wb[2]; pf[2].u[3] = wb[3];
      pf[3].u[0] = wb[4]; pf[3].u[1] = wb[5]; pf[3].u[2] = wb[6]; pf[3].u[3] = wb[7];

      __builtin_amdgcn_s_setprio(1);
#pragma unroll
      for (int kg = 0; kg < 4; ++kg) {
#pragma unroll
        for (int db = 0; db < 4; ++db) {
          int row = db * 32 + l31;
          half8 vf = *(const half8*)(Vc + row * 128 + ((kg * 32 + hi * 16) ^ ((row & 7) << 4)));
          oa[db] = __builtin_amdgcn_mfma_f32_32x32x16_f16(vf, pf[kg].v, oa[db], 0, 0, 0);
        }
      }
      __builtin_amdgcn_s_setprio(0);
    }

    asm volatile("s_waitcnt vmcnt(0)" ::: "memory");
    __syncthreads();
    cur ^= 1;
  }

  __syncthreads();
  float lt = lsum + __shfl_xor(lsum, 32);
  float invl = 1.0f / lt;
  char* Ob = smem + w * 8192;
#pragma unroll
  for (int db = 0; db < 4; ++db)
#pragma unroll
    for (int r = 0; r < 16; ++r) {
      int d = db * 32 + (r & 3) + 8 * (r >> 2) + 4 * hi;
      *(_Float16*)(Ob + l31 * 256 + ((2 * d) ^ ((l31 & 7) << 4))) = (_Float16)(oa[db][r] * invl);
    }
  __builtin_amdgcn_s_waitcnt(0);
  const int b = bh >> 4, h = bh & 15;
#pragma unroll
  for (int i = 0; i < 8; ++i) {
    int cidx = i * 64 + lane;
    int row = cidx >> 4;
    int colb = (cidx & 15) * 16;
    half8 v = *(const half8*)(Ob + row * 256 + (colb ^ ((row & 7) << 4)));
    int s = qw + row;
    *(half8*)(ctx + ((size_t)(b * SEQ + s)) * D_MODEL + h * DK + colb / 2) = v;
  }
}

// ---------------- launch ----------------
extern "C" void kernel_launch(void* const* d_in, const int* in_sizes, int n_in,
                              void* d_out, int out_size, void* d_ws, size_t ws_size,
                              hipStream_t stream) {
  const float* x = (const float*)d_in[0];
  const int* pos = (const int*)d_in[1];
  const float* Wq = (const float*)d_in[2];
  const float* Wk = (const float*)d_in[3];
  const float* Wv = (const float*)d_in[4];
  const float* Wo = (const float*)d_in[5];
  float* out = (float*)d_out;

  const size_t SZ_XH = (size_t)M_TOT * D_MODEL;
  const size_t SZ_W = (size_t)D_MODEL * D_MODEL;

  _Float16* xh = (_Float16*)d_ws;
  _Float16* wqh = xh + SZ_XH;        // Wq,Wk,Wv,Wo contiguous
  _Float16* woh = wqh + 3 * SZ_W;
  _Float16* Qh = woh + SZ_W;
  _Float16* Kh = Qh + SZ_HEAD;
  _Float16* Vth = Kh + SZ_HEAD;
  _Float16* ctx = xh;                 // alias: xh dead after QKV GEMM
  float2* tab = (float2*)d_out;       // first 1MB of out; fully overwritten by O-GEMM

  cvt_f32_f16<<<2048, 256, 0, stream>>>(x, xh, (int)(SZ_XH / 8));
  cvt4_f32_f16<<<2048, 256, 0, stream>>>(Wq, Wk, Wv, Wo, wqh);
  build_tab<<<SEQ * 64 / 256, 256, 0, stream>>>(pos, tab);

  // fused QKV projection: N = 6144, 256x256 tiles -> 32x24 = 768 blocks
  gemm8p<3><<<768, 512, 0, stream>>>(xh, wqh, Qh, tab, 3 * D_MODEL, D_MODEL);

  attn_kernel<<<(SEQ / 256) * BH, 512, 0, stream>>>(Qh, Kh, Vth, ctx);

  // output projection: 32x8 = 256 blocks
  gemm8p<2><<<256, 512, 0, stream>>>(ctx, woh, out, nullptr, D_MODEL, D_MODEL);
}